// Round 1
// baseline (11204.404 us; speedup 1.0000x reference)
//
#include <hip/hip_runtime.h>
#include <cstdint>
#include <cstddef>

#define NENV 4096
#define SEQ  128
#define LATENT 64
#define EMB  256
#define HID  1024
#define SA   2

typedef _Float16 half8 __attribute__((ext_vector_type(8)));
typedef float f32x4 __attribute__((ext_vector_type(4)));

__device__ __forceinline__ float sigmoid_f(float x){ return 1.0f/(1.0f + __expf(-x)); }

// ---------- pre-pass: transpose + fp32->fp16 convert: in [K][C] -> out [C][K] ----------
__global__ void transpose_cvt_kernel(const float* __restrict__ in, _Float16* __restrict__ out,
                                     int K, int C){
  int n = K*C;
  for (int i = blockIdx.x*blockDim.x + threadIdx.x; i < n; i += gridDim.x*blockDim.x){
    int c = i / K;
    int k = i - c*K;
    out[i] = (_Float16)in[(size_t)k*C + c];
  }
}

__global__ void init_h_kernel(const float* __restrict__ rnn, float* __restrict__ h32,
                              _Float16* __restrict__ h16){
  int n = NENV*HID;
  for (int i = blockIdx.x*blockDim.x + threadIdx.x; i < n; i += gridDim.x*blockDim.x){
    float v = rnn[i];
    h32[i] = v;
    h16[i] = (_Float16)v;
  }
}

// ---------- fused GRU: gi = x2@wih, gh = h@whh, gates, h update ----------
// Block: 256 threads (4 waves), output tile 64 rows x 64 h-cols.
// Weight layout: wT [3*HID][K] (row = gate*HID + col, k contiguous).
__device__ __forceinline__ void gru_kloop(
    const _Float16* __restrict__ A, const _Float16* __restrict__ W, int K,
    int r0, int c0, int arow, int aseg, int m, int q, int n0,
    _Float16* As, _Float16* Ws0, _Float16* Ws1, _Float16* Ws2,
    f32x4* acc_r, f32x4* acc_z, f32x4* accn)
{
  for (int k0 = 0; k0 < K; k0 += 32){
    half8 la  = *(const half8*)(A + (size_t)(r0 + arow)*K + k0 + aseg*8);
    half8 lw0 = *(const half8*)(W + (size_t)(          c0 + arow)*K + k0 + aseg*8);
    half8 lw1 = *(const half8*)(W + (size_t)(HID     + c0 + arow)*K + k0 + aseg*8);
    half8 lw2 = *(const half8*)(W + (size_t)(2*HID   + c0 + arow)*K + k0 + aseg*8);
    __syncthreads();
    *(half8*)&As [arow*40 + aseg*8] = la;
    *(half8*)&Ws0[arow*40 + aseg*8] = lw0;
    *(half8*)&Ws1[arow*40 + aseg*8] = lw1;
    *(half8*)&Ws2[arow*40 + aseg*8] = lw2;
    __syncthreads();
    half8 br = *(const half8*)&Ws0[(n0+m)*40 + q*8];
    half8 bz = *(const half8*)&Ws1[(n0+m)*40 + q*8];
    half8 bn = *(const half8*)&Ws2[(n0+m)*40 + q*8];
#pragma unroll
    for (int mt = 0; mt < 4; ++mt){
      half8 a = *(const half8*)&As[(mt*16 + m)*40 + q*8];
      acc_r[mt] = __builtin_amdgcn_mfma_f32_16x16x32_f16(a, br, acc_r[mt], 0, 0, 0);
      acc_z[mt] = __builtin_amdgcn_mfma_f32_16x16x32_f16(a, bz, acc_z[mt], 0, 0, 0);
      accn[mt]  = __builtin_amdgcn_mfma_f32_16x16x32_f16(a, bn, accn[mt], 0, 0, 0);
    }
  }
}

__global__ __launch_bounds__(256, 4) void gru_kernel(
    const _Float16* __restrict__ x2h, const _Float16* __restrict__ hcur16,
    const _Float16* __restrict__ wihT, const _Float16* __restrict__ whhT,
    const float* __restrict__ bih, const float* __restrict__ bhh,
    float* __restrict__ h32, _Float16* __restrict__ hnxt16)
{
  __shared__ _Float16 As[64*40];
  __shared__ _Float16 Ws0[64*40];
  __shared__ _Float16 Ws1[64*40];
  __shared__ _Float16 Ws2[64*40];
  const int r0 = blockIdx.x*64, c0 = blockIdx.y*64;
  const int tid = threadIdx.x;
  const int lane = tid & 63, wave = tid >> 6;
  const int m = lane & 15, q = lane >> 4, n0 = wave*16;
  const int arow = tid >> 2, aseg = tid & 3;

  f32x4 zero4 = {0.f, 0.f, 0.f, 0.f};
  f32x4 acc_r[4], acc_z[4], acc_in[4], acc_hn[4];
#pragma unroll
  for (int i = 0; i < 4; ++i){ acc_r[i]=zero4; acc_z[i]=zero4; acc_in[i]=zero4; acc_hn[i]=zero4; }

  gru_kloop(x2h,    wihT, EMB, r0, c0, arow, aseg, m, q, n0, As, Ws0, Ws1, Ws2, acc_r, acc_z, acc_in);
  gru_kloop(hcur16, whhT, HID, r0, c0, arow, aseg, m, q, n0, As, Ws0, Ws1, Ws2, acc_r, acc_z, acc_hn);

  const int gc = c0 + n0 + m;
  float b_r  = bih[gc]         + bhh[gc];
  float b_z  = bih[gc + HID]   + bhh[gc + HID];
  float b_in = bih[gc + 2*HID];
  float b_hn = bhh[gc + 2*HID];
#pragma unroll
  for (int mt = 0; mt < 4; ++mt){
#pragma unroll
    for (int r = 0; r < 4; ++r){
      int grow = r0 + mt*16 + q*4 + r;
      float rr = sigmoid_f(acc_r[mt][r] + b_r);
      float u  = sigmoid_f(acc_z[mt][r] + b_z);
      float nn = tanhf(acc_in[mt][r] + b_in + rr*(acc_hn[mt][r] + b_hn));
      size_t idx = (size_t)grow*HID + gc;
      float hold = h32[idx];
      float hnew = (1.0f - u)*nn + u*hold;
      h32[idx] = hnew;
      hnxt16[idx] = (_Float16)hnew;
    }
  }
}

// ---------- o1 = relu(h @ w3 + b3), [4096,1024]@[1024,512] ----------
__global__ __launch_bounds__(256, 4) void out1_kernel(
    const _Float16* __restrict__ h16, const _Float16* __restrict__ w3T,
    const float* __restrict__ b3, float* __restrict__ o1)
{
  __shared__ _Float16 As[64*40];
  __shared__ _Float16 Ws[64*40];
  const int r0 = blockIdx.x*64, c0 = blockIdx.y*64;
  const int tid = threadIdx.x;
  const int lane = tid & 63, wave = tid >> 6;
  const int m = lane & 15, q = lane >> 4, n0 = wave*16;
  const int arow = tid >> 2, aseg = tid & 3;

  f32x4 zero4 = {0.f, 0.f, 0.f, 0.f};
  f32x4 acc[4];
#pragma unroll
  for (int i = 0; i < 4; ++i) acc[i] = zero4;

  for (int k0 = 0; k0 < HID; k0 += 32){
    half8 la = *(const half8*)(h16 + (size_t)(r0 + arow)*HID + k0 + aseg*8);
    half8 lw = *(const half8*)(w3T + (size_t)(c0 + arow)*HID + k0 + aseg*8);
    __syncthreads();
    *(half8*)&As[arow*40 + aseg*8] = la;
    *(half8*)&Ws[arow*40 + aseg*8] = lw;
    __syncthreads();
    half8 b = *(const half8*)&Ws[(n0+m)*40 + q*8];
#pragma unroll
    for (int mt = 0; mt < 4; ++mt){
      half8 a = *(const half8*)&As[(mt*16 + m)*40 + q*8];
      acc[mt] = __builtin_amdgcn_mfma_f32_16x16x32_f16(a, b, acc[mt], 0, 0, 0);
    }
  }
  const int gc = c0 + n0 + m;
  float bb = b3[gc];
#pragma unroll
  for (int mt = 0; mt < 4; ++mt){
#pragma unroll
    for (int r = 0; r < 4; ++r){
      int grow = r0 + mt*16 + q*4 + r;
      o1[(size_t)grow*(HID/2) + gc] = fmaxf(acc[mt][r] + bb, 0.f);
    }
  }
}

// ---------- tail of step t fused with head of step t+1 ----------
// mode 0: init  (state=-2, compute x2 for t=0; no output head)
// mode 1: mid   (o = tanh(o1@w4+b4) -> out[:,t,:]; then x2 for t+1)
// mode 2: last  (output head only)
__global__ void tail_head_kernel(
    const float* __restrict__ o1, const float* __restrict__ w4, const float* __restrict__ b4,
    const float* __restrict__ z,  const float* __restrict__ w1, const float* __restrict__ b1,
    const float* __restrict__ w2, const float* __restrict__ b2,
    _Float16* __restrict__ x2h, float* __restrict__ out, int t, int mode)
{
  __shared__ float sw2[32*256];   // 32 KB
  __shared__ float sw1[66*32];    // 8.4 KB
  __shared__ float sz[16][64];
  __shared__ float sx1[16][32];
  __shared__ float sst[16][2];
  const int tid = threadIdx.x;
  const int r0 = blockIdx.x*16;

  if (mode != 2){
    for (int i = tid; i < 66*32; i += 256) sw1[i] = w1[i];
    for (int i = tid; i < 32*256; i += 256) sw2[i] = w2[i];
    int zt = (mode == 0) ? 0 : (t + 1);
    for (int i = tid; i < 16*64; i += 256){
      int r = i >> 6, k = i & 63;
      sz[r][k] = z[(size_t)(r0 + r)*SEQ*LATENT + zt*LATENT + k];
    }
  }

  if (mode != 0){
    // output head: 16 threads per row, 32 k each over K=512
    int r = tid >> 4, p = tid & 15;
    const float* orow = o1 + (size_t)(r0 + r)*(HID/2);
    float a0 = 0.f, a1 = 0.f;
    for (int k = p*32; k < p*32 + 32; ++k){
      float v = orow[k];
      a0 += v*w4[k*2];
      a1 += v*w4[k*2 + 1];
    }
#pragma unroll
    for (int off = 1; off < 16; off <<= 1){
      a0 += __shfl_xor(a0, off);
      a1 += __shfl_xor(a1, off);
    }
    if (p == 0){
      a0 = tanhf(a0 + b4[0]);
      a1 = tanhf(a1 + b4[1]);
      out[(size_t)(r0 + r)*SEQ*SA + t*SA + 0] = a0;
      out[(size_t)(r0 + r)*SEQ*SA + t*SA + 1] = a1;
      sst[r][0] = a0; sst[r][1] = a1;
    }
  } else {
    if (tid < 32) sst[tid >> 1][tid & 1] = -2.0f;
  }
  __syncthreads();

  if (mode != 2){
    // x1 = relu([state, z_t] @ w1 + b1) : 16 rows x 32 cols
    for (int it = tid; it < 16*32; it += 256){
      int r = it >> 5, j = it & 31;
      float acc = b1[j];
      acc += sst[r][0]*sw1[0*32 + j] + sst[r][1]*sw1[1*32 + j];
#pragma unroll 8
      for (int k = 0; k < 64; ++k) acc += sz[r][k]*sw1[(k + 2)*32 + j];
      sx1[r][j] = fmaxf(acc, 0.f);
    }
    __syncthreads();
    // x2 = relu(x1 @ w2 + b2) : 16 rows x 256 cols, one col per thread
    int col = tid;
    for (int r = 0; r < 16; ++r){
      float acc = b2[col];
#pragma unroll
      for (int k = 0; k < 32; ++k) acc += sx1[r][k]*sw2[k*256 + col];
      x2h[(size_t)(r0 + r)*EMB + col] = (_Float16)fmaxf(acc, 0.f);
    }
  }
}

extern "C" void kernel_launch(void* const* d_in, const int* in_sizes, int n_in,
                              void* d_out, int out_size, void* d_ws, size_t ws_size,
                              hipStream_t stream) {
  const float* z   = (const float*)d_in[0];
  const float* rnn = (const float*)d_in[1];
  const float* w1  = (const float*)d_in[2];
  const float* b1  = (const float*)d_in[3];
  const float* w2  = (const float*)d_in[4];
  const float* b2  = (const float*)d_in[5];
  const float* wih = (const float*)d_in[6];
  const float* bih = (const float*)d_in[7];
  const float* whh = (const float*)d_in[8];
  const float* bhh = (const float*)d_in[9];
  const float* w3  = (const float*)d_in[10];
  const float* b3  = (const float*)d_in[11];
  const float* w4  = (const float*)d_in[12];
  const float* b4  = (const float*)d_in[13];
  float* out = (float*)d_out;

  char* ws = (char*)d_ws;
  _Float16* wihT = (_Float16*)ws;                 ws += (size_t)3*HID*EMB*2;     // [3072][256]
  _Float16* whhT = (_Float16*)ws;                 ws += (size_t)3*HID*HID*2;     // [3072][1024]
  _Float16* w3T  = (_Float16*)ws;                 ws += (size_t)(HID/2)*HID*2;   // [512][1024]
  _Float16* h16a = (_Float16*)ws;                 ws += (size_t)NENV*HID*2;
  _Float16* h16b = (_Float16*)ws;                 ws += (size_t)NENV*HID*2;
  float*    h32  = (float*)ws;                    ws += (size_t)NENV*HID*4;
  _Float16* x2h  = (_Float16*)ws;                 ws += (size_t)NENV*EMB*2;
  float*    o1   = (float*)ws;                    ws += (size_t)NENV*(HID/2)*4;

  // pre-pass: weight transposes + h init
  transpose_cvt_kernel<<<512, 256, 0, stream>>>(wih, wihT, EMB, 3*HID);
  transpose_cvt_kernel<<<1024, 256, 0, stream>>>(whh, whhT, HID, 3*HID);
  transpose_cvt_kernel<<<256, 256, 0, stream>>>(w3, w3T, HID, HID/2);
  init_h_kernel<<<1024, 256, 0, stream>>>(rnn, h32, h16a);

  // head for t=0 (state = -2)
  tail_head_kernel<<<NENV/16, 256, 0, stream>>>(o1, w4, b4, z, w1, b1, w2, b2, x2h, out, 0, 0);

  for (int t = 0; t < SEQ; ++t){
    _Float16* hc = (t & 1) ? h16b : h16a;
    _Float16* hn = (t & 1) ? h16a : h16b;
    gru_kernel<<<dim3(NENV/64, HID/64), 256, 0, stream>>>(x2h, hc, wihT, whhT, bih, bhh, h32, hn);
    out1_kernel<<<dim3(NENV/64, (HID/2)/64), 256, 0, stream>>>(hn, w3T, b3, o1);
    tail_head_kernel<<<NENV/16, 256, 0, stream>>>(o1, w4, b4, z, w1, b1, w2, b2, x2h, out,
                                                  t, (t < SEQ - 1) ? 1 : 2);
  }

  // final hidden state -> second output
  hipMemcpyAsync(out + (size_t)NENV*SEQ*SA, h32, (size_t)NENV*HID*sizeof(float),
                 hipMemcpyDeviceToDevice, stream);
}